// Round 1
// baseline (1081.304 us; speedup 1.0000x reference)
//
#include <hip/hip_runtime.h>
#include <hip/hip_bf16.h>
#include <math.h>

// Problem dims (fixed by reference)
#define B_ 16
#define T_ 1024
#define C_ 768
#define H_ 64

// ---------------------------------------------------------------------------
// Kernel 1: fused QKV projection.
// One block per (b,t) row of x. 192 threads = 3 waves; thread t: matrix w=t/64,
// column col=t%64. x row staged in LDS (768 f32 = 3 KB), W column reads are
// coalesced across the wave (threads col=0..63 read contiguous 256B at each c).
// ---------------------------------------------------------------------------
__global__ __launch_bounds__(192) void qkv_kernel(
    const float* __restrict__ x,
    const float* __restrict__ Wq, const float* __restrict__ bq,
    const float* __restrict__ Wk, const float* __restrict__ bk,
    const float* __restrict__ Wv, const float* __restrict__ bv,
    float* __restrict__ q, float* __restrict__ k, float* __restrict__ v) {
  __shared__ float xs[C_];
  const int row = blockIdx.x;           // 0..B*T-1
  const int tid = threadIdx.x;          // 0..191
  const float* xr = x + (size_t)row * C_;
  for (int i = tid; i < C_; i += 192) xs[i] = xr[i];
  __syncthreads();

  const int w = tid >> 6;               // 0=q, 1=k, 2=v
  const int col = tid & 63;
  const float* W = (w == 0) ? Wq : (w == 1) ? Wk : Wv;
  const float* bias = (w == 0) ? bq : (w == 1) ? bk : bv;

  float acc = bias[col];
  #pragma unroll 8
  for (int c = 0; c < C_; ++c) {
    acc = fmaf(xs[c], W[c * H_ + col], acc);
  }
  float* out = (w == 0) ? q : (w == 1) ? k : v;
  out[(size_t)row * H_ + col] = acc;
}

// ---------------------------------------------------------------------------
// Kernel 2: causal attention, one wave (64 threads) per (b, t) query row.
// Thread h owns dimension h. Per key row s<=t: coalesced 256B k/v row read,
// wave-wide shuffle reduce for the dot product, online softmax in registers.
// K/V per batch = 256 KB -> L2 resident across the 1024 blocks of that batch.
// ---------------------------------------------------------------------------
__global__ __launch_bounds__(64) void attn_kernel(
    const float* __restrict__ q, const float* __restrict__ k,
    const float* __restrict__ v, float* __restrict__ out) {
  const int t = blockIdx.x;   // query position
  const int b = blockIdx.y;   // batch
  const int h = threadIdx.x;  // 0..63

  const float scale = 0.125f; // 1/sqrt(64)
  const float* kb = k + (size_t)b * T_ * H_;
  const float* vb = v + (size_t)b * T_ * H_;

  const float qh = q[((size_t)b * T_ + t) * H_ + h] * scale;

  float m = -INFINITY;  // running max
  float l = 0.0f;       // running denom
  float acc = 0.0f;     // running numerator for dim h

  for (int s = 0; s <= t; ++s) {
    float p = qh * kb[(size_t)s * H_ + h];
    // reduce across the 64-lane wave
    #pragma unroll
    for (int off = 32; off > 0; off >>= 1) p += __shfl_xor(p, off);
    // p now holds the full dot product (already scaled) on every lane
    const float vn = vb[(size_t)s * H_ + h];
    const float mn = fmaxf(m, p);
    const float wgt = __expf(p - mn);
    const float corr = __expf(m - mn);   // exp(-inf)=0 handles first iter
    l = l * corr + wgt;
    acc = acc * corr + wgt * vn;
    m = mn;
  }

  out[((size_t)b * T_ + t) * H_ + h] = acc / l;
}

// ---------------------------------------------------------------------------
extern "C" void kernel_launch(void* const* d_in, const int* in_sizes, int n_in,
                              void* d_out, int out_size, void* d_ws, size_t ws_size,
                              hipStream_t stream) {
  const float* x  = (const float*)d_in[0];
  const float* Wq = (const float*)d_in[1];
  const float* bq = (const float*)d_in[2];
  const float* Wk = (const float*)d_in[3];
  const float* bk = (const float*)d_in[4];
  const float* Wv = (const float*)d_in[5];
  const float* bv = (const float*)d_in[6];
  float* out = (float*)d_out;

  // workspace: q, k, v each B*T*H f32 (4 MB) -> 12 MB total
  const size_t qkv_elems = (size_t)B_ * T_ * H_;
  float* q = (float*)d_ws;
  float* k = q + qkv_elems;
  float* v = k + qkv_elems;

  qkv_kernel<<<dim3(B_ * T_), dim3(192), 0, stream>>>(x, Wq, bq, Wk, bk, Wv, bv,
                                                      q, k, v);
  attn_kernel<<<dim3(T_, B_), dim3(64), 0, stream>>>(q, k, v, out);
}

// Round 2
// 97.121 us; speedup vs baseline: 11.1336x; 11.1336x over previous
//
#include <hip/hip_runtime.h>
#include <math.h>

// Problem dims (fixed by reference)
#define B_ 16
#define T_ 1024
#define C_ 768
#define H_ 64

typedef __attribute__((ext_vector_type(8))) short bf16x8;
typedef __attribute__((ext_vector_type(4))) float f32x4;

// fp32 -> bf16 (round-to-nearest-even, no NaN special-casing; inputs are sane)
__device__ __forceinline__ short f2bf(float f) {
  union { float f; unsigned u; } un;
  un.f = f;
  unsigned r = un.u + 0x7FFFu + ((un.u >> 16) & 1u);
  return (short)(r >> 16);
}

// ---------------------------------------------------------------------------
// Kernel 1: W prep — Wt[mat][n][k] = W_mat[k][n] as bf16.  (3*64*768 elems)
// ---------------------------------------------------------------------------
__global__ __launch_bounds__(256) void prep_w(
    const float* __restrict__ Wq, const float* __restrict__ Wk,
    const float* __restrict__ Wv, short* __restrict__ wt) {
  int idx = blockIdx.x * 256 + threadIdx.x;
  if (idx >= 3 * H_ * C_) return;
  int k = idx % C_;
  int n = (idx / C_) % H_;
  int mat = idx / (C_ * H_);
  const float* W = (mat == 0) ? Wq : (mat == 1) ? Wk : Wv;
  wt[idx] = f2bf(W[(size_t)k * H_ + n]);
}

// ---------------------------------------------------------------------------
// Kernel 2: QKV projection as bf16 MFMA GEMM.  M=16384, K=768, N=64 per matrix.
// One wave per (16-row tile, matrix). A-frag: fp32 x + inline cvt. B-frag: Wt.
// ---------------------------------------------------------------------------
__global__ __launch_bounds__(256) void qkv_gemm(
    const float* __restrict__ x, const short* __restrict__ wt,
    const float* __restrict__ bq, const float* __restrict__ bk,
    const float* __restrict__ bv,
    short* __restrict__ qb, short* __restrict__ kb, short* __restrict__ vb) {
  const int wid = blockIdx.x * 4 + (threadIdx.x >> 6);  // 0..3071
  const int mat = wid % 3;
  const int rt = wid / 3;              // 0..1023 row tiles of 16
  const int l = threadIdx.x & 63;
  const int lo = l & 15, hi = l >> 4;

  const float* xrow = x + (size_t)(rt * 16 + lo) * C_;
  const short* wmat = wt + (size_t)mat * H_ * C_;

  f32x4 acc[4];
  #pragma unroll
  for (int ct = 0; ct < 4; ++ct) acc[ct] = (f32x4){0.f, 0.f, 0.f, 0.f};

  for (int kc = 0; kc < C_ / 32; ++kc) {
    const int kbase = kc * 32 + hi * 8;
    f32x4 f0 = *(const f32x4*)(xrow + kbase);
    f32x4 f1 = *(const f32x4*)(xrow + kbase + 4);
    bf16x8 af;
    #pragma unroll
    for (int j = 0; j < 4; ++j) { af[j] = f2bf(f0[j]); af[4 + j] = f2bf(f1[j]); }
    #pragma unroll
    for (int ct = 0; ct < 4; ++ct) {
      bf16x8 bf = *(const bf16x8*)(wmat + (size_t)(ct * 16 + lo) * C_ + kbase);
      acc[ct] = __builtin_amdgcn_mfma_f32_16x16x32_bf16(af, bf, acc[ct], 0, 0, 0);
    }
  }

  const float* bias = (mat == 0) ? bq : (mat == 1) ? bk : bv;
  short* ob = (mat == 0) ? qb : (mat == 1) ? kb : vb;
  #pragma unroll
  for (int ct = 0; ct < 4; ++ct) {
    const float bv_ = bias[ct * 16 + lo];
    #pragma unroll
    for (int r = 0; r < 4; ++r) {
      const int row = rt * 16 + hi * 4 + r;
      ob[(size_t)row * H_ + ct * 16 + lo] = f2bf(acc[ct][r] + bv_);
    }
  }
}

// ---------------------------------------------------------------------------
// Kernel 3: V transpose — Vt[b][n][t] = v[b][t][n] (bf16), via LDS tiles.
// ---------------------------------------------------------------------------
__global__ __launch_bounds__(256) void vtrans(const short* __restrict__ vb,
                                              short* __restrict__ vt) {
  __shared__ short tile[64][66];  // row stride 132 B to spread banks
  const int b = blockIdx.y;
  const int tb = blockIdx.x * 64;
  const int tid = threadIdx.x;

  {
    const int tt = tid >> 2, c = (tid & 3) * 16;
    const short* src = vb + (size_t)(b * T_ + tb + tt) * H_ + c;
    bf16x8 v0 = *(const bf16x8*)(src);
    bf16x8 v1 = *(const bf16x8*)(src + 8);
    #pragma unroll
    for (int j = 0; j < 8; ++j) { tile[tt][c + j] = v0[j]; tile[tt][c + 8 + j] = v1[j]; }
  }
  __syncthreads();
  {
    const int n = tid >> 2, toff = (tid & 3) * 16;
    short* dst = vt + ((size_t)(b * H_ + n)) * T_ + tb + toff;
    bf16x8 o0, o1;
    #pragma unroll
    for (int j = 0; j < 8; ++j) { o0[j] = tile[toff + j][n]; o1[j] = tile[toff + 8 + j][n]; }
    *(bf16x8*)(dst) = o0;
    *(bf16x8*)(dst + 8) = o1;
  }
}

// ---------------------------------------------------------------------------
// Kernel 4: flash attention. 1 wave per 16 q-rows; KV tiles of 64.
// QK^T and PV via mfma_f32_16x16x32_bf16; online softmax wave-parallel.
// ---------------------------------------------------------------------------
__global__ __launch_bounds__(64) void flash(
    const short* __restrict__ qb, const short* __restrict__ kb,
    const short* __restrict__ vt, float* __restrict__ out) {
  __shared__ short p_lds[16][72];  // row stride 144 B (16B-aligned, 2-way banks)
  const int qt = (int)gridDim.x - 1 - (int)blockIdx.x;  // reverse: big tiles first
  const int b = blockIdx.y;
  const int l = threadIdx.x;
  const int lo = l & 15, hi = l >> 4;

  // Q fragments (K-chunks of 32): lane holds Q[row=lo][k = kc*32 + hi*8 + j]
  const short* qrow = qb + (size_t)(b * T_ + qt * 16 + lo) * H_;
  bf16x8 qf0 = *(const bf16x8*)(qrow + hi * 8);
  bf16x8 qf1 = *(const bf16x8*)(qrow + 32 + hi * 8);

  float m[4], lsum[4];
  f32x4 oacc[4];
  #pragma unroll
  for (int r = 0; r < 4; ++r) { m[r] = -1e30f; lsum[r] = 0.f; }
  #pragma unroll
  for (int dt = 0; dt < 4; ++dt) oacc[dt] = (f32x4){0.f, 0.f, 0.f, 0.f};

  const int ntiles = qt >> 2;   // index of diagonal KV tile
  const int qr = qt & 3;        // q-subtile offset within diagonal tile

  for (int kvt = 0; kvt <= ntiles; ++kvt) {
    const bool diag = (kvt == ntiles);
    const int nct = diag ? (qr + 1) : 4;  // wave-uniform

    // S = Q K^T  (16 x 64), 4 col-tiles of 16 keys
    f32x4 sv[4];
    #pragma unroll
    for (int ct = 0; ct < 4; ++ct) sv[ct] = (f32x4){0.f, 0.f, 0.f, 0.f};
    #pragma unroll
    for (int ct = 0; ct < 4; ++ct) {
      if (ct < nct) {
        const short* krow = kb + (size_t)(b * T_ + kvt * 64 + ct * 16 + lo) * H_;
        bf16x8 kf0 = *(const bf16x8*)(krow + hi * 8);
        bf16x8 kf1 = *(const bf16x8*)(krow + 32 + hi * 8);
        sv[ct] = __builtin_amdgcn_mfma_f32_16x16x32_bf16(qf0, kf0, sv[ct], 0, 0, 0);
        sv[ct] = __builtin_amdgcn_mfma_f32_16x16x32_bf16(qf1, kf1, sv[ct], 0, 0, 0);
      }
    }

    // scale + causal mask
    #pragma unroll
    for (int ct = 0; ct < 4; ++ct) {
      #pragma unroll
      for (int r = 0; r < 4; ++r) {
        float s = (ct < nct) ? sv[ct][r] * 0.125f : -1e30f;
        if (diag && ct == qr && lo > hi * 4 + r) s = -1e30f;
        sv[ct][r] = s;
      }
    }

    // online softmax per row r (rows hi*4+r, cols spread over 16-lane group)
    #pragma unroll
    for (int r = 0; r < 4; ++r) {
      float tmax = fmaxf(fmaxf(sv[0][r], sv[1][r]), fmaxf(sv[2][r], sv[3][r]));
      #pragma unroll
      for (int msk = 1; msk < 16; msk <<= 1) tmax = fmaxf(tmax, __shfl_xor(tmax, msk));
      const float mn = fmaxf(m[r], tmax);
      const float corr = __expf(m[r] - mn);
      m[r] = mn;
      float psum = 0.f;
      #pragma unroll
      for (int ct = 0; ct < 4; ++ct) {
        float p = __expf(sv[ct][r] - mn);
        sv[ct][r] = p;
        psum += p;
      }
      #pragma unroll
      for (int msk = 1; msk < 16; msk <<= 1) psum += __shfl_xor(psum, msk);
      lsum[r] = lsum[r] * corr + psum;
      #pragma unroll
      for (int dt = 0; dt < 4; ++dt) oacc[dt][r] *= corr;
    }

    // P -> bf16 -> LDS (layout [q-row][kv])
    #pragma unroll
    for (int ct = 0; ct < 4; ++ct) {
      #pragma unroll
      for (int r = 0; r < 4; ++r) {
        p_lds[hi * 4 + r][ct * 16 + lo] = f2bf(sv[ct][r]);
      }
    }
    // same wave: DS ops in order; compiler inserts lgkmcnt waits before use

    // O += P V : A-frag from p_lds, B-frag from Vt (contiguous 16B/lane)
    bf16x8 pa0 = *(const bf16x8*)(&p_lds[lo][hi * 8]);
    bf16x8 pa1 = *(const bf16x8*)(&p_lds[lo][32 + hi * 8]);
    #pragma unroll
    for (int dt = 0; dt < 4; ++dt) {
      const short* vrow = vt + (size_t)(b * H_ + dt * 16 + lo) * T_ + kvt * 64;
      bf16x8 vf0 = *(const bf16x8*)(vrow + hi * 8);
      bf16x8 vf1 = *(const bf16x8*)(vrow + 32 + hi * 8);
      oacc[dt] = __builtin_amdgcn_mfma_f32_16x16x32_bf16(pa0, vf0, oacc[dt], 0, 0, 0);
      oacc[dt] = __builtin_amdgcn_mfma_f32_16x16x32_bf16(pa1, vf1, oacc[dt], 0, 0, 0);
    }
  }

  // epilogue: out fp32
  #pragma unroll
  for (int dt = 0; dt < 4; ++dt) {
    #pragma unroll
    for (int r = 0; r < 4; ++r) {
      const int row = qt * 16 + hi * 4 + r;
      out[(size_t)(b * T_ + row) * H_ + dt * 16 + lo] = oacc[dt][r] / lsum[r];
    }
  }
}

// ---------------------------------------------------------------------------
extern "C" void kernel_launch(void* const* d_in, const int* in_sizes, int n_in,
                              void* d_out, int out_size, void* d_ws, size_t ws_size,
                              hipStream_t stream) {
  const float* x  = (const float*)d_in[0];
  const float* Wq = (const float*)d_in[1];
  const float* bq = (const float*)d_in[2];
  const float* Wk = (const float*)d_in[3];
  const float* bk = (const float*)d_in[4];
  const float* Wv = (const float*)d_in[5];
  const float* bv = (const float*)d_in[6];
  float* out = (float*)d_out;

  // workspace layout (shorts): wt | qb | kb | vb | vt
  short* wt = (short*)d_ws;
  short* qb = wt + (size_t)3 * H_ * C_;          // 147456
  short* kb = qb + (size_t)B_ * T_ * H_;         // +1M
  short* vb = kb + (size_t)B_ * T_ * H_;
  short* vtb = vb + (size_t)B_ * T_ * H_;

  prep_w<<<dim3((3 * H_ * C_ + 255) / 256), dim3(256), 0, stream>>>(Wq, Wk, Wv, wt);
  qkv_gemm<<<dim3(768), dim3(256), 0, stream>>>(x, wt, bq, bk, bv, qb, kb, vb);
  vtrans<<<dim3(T_ / 64, B_), dim3(256), 0, stream>>>(vb, vtb);
  flash<<<dim3(T_ / 16, B_), dim3(64), 0, stream>>>(qb, kb, vtb, out);
}

// Round 3
// 92.553 us; speedup vs baseline: 11.6831x; 1.0494x over previous
//
#include <hip/hip_runtime.h>
#include <math.h>

// Problem dims (fixed by reference)
#define B_ 16
#define T_ 1024
#define C_ 768
#define H_ 64

typedef __attribute__((ext_vector_type(8))) short bf16x8;
typedef __attribute__((ext_vector_type(4))) float f32x4;

// fp32 -> bf16 (round-to-nearest-even)
__device__ __forceinline__ short f2bf(float f) {
  union { float f; unsigned u; } un;
  un.f = f;
  unsigned r = un.u + 0x7FFFu + ((un.u >> 16) & 1u);
  return (short)(r >> 16);
}

// ---------------------------------------------------------------------------
// Kernel 1: W prep — Wt[mat][n][k] = W_mat[k][n] as bf16.  (3*64*768 elems)
// ---------------------------------------------------------------------------
__global__ __launch_bounds__(256) void prep_w(
    const float* __restrict__ Wq, const float* __restrict__ Wk,
    const float* __restrict__ Wv, short* __restrict__ wt) {
  int idx = blockIdx.x * 256 + threadIdx.x;
  if (idx >= 3 * H_ * C_) return;
  int k = idx % C_;
  int n = (idx / C_) % H_;
  int mat = idx / (C_ * H_);
  const float* W = (mat == 0) ? Wq : (mat == 1) ? Wk : Wv;
  wt[idx] = f2bf(W[(size_t)k * H_ + n]);
}

// ---------------------------------------------------------------------------
// Kernel 2: QKV projection, bf16 MFMA, software-pipelined load groups.
// One wave per (16-row tile, matrix). Group = 64 k-elems: 4 f32x4 x-loads +
// 8 bf16x8 W-loads, double-buffered so ~12 loads are in flight during MFMAs.
// All register arrays static-indexed via full unroll (no scratch).
// ---------------------------------------------------------------------------
struct Grp {
  f32x4 x[4];
  bf16x8 b[8];
};

__device__ __forceinline__ Grp loadg(const float* __restrict__ xrow,
                                     const short* __restrict__ wmat,
                                     int g, int lo) {
  Grp r;
  #pragma unroll
  for (int c = 0; c < 2; ++c) {
    const int kbase = g * 64 + c * 32;
    r.x[c * 2]     = *(const f32x4*)(xrow + kbase);
    r.x[c * 2 + 1] = *(const f32x4*)(xrow + kbase + 4);
    #pragma unroll
    for (int ct = 0; ct < 4; ++ct)
      r.b[c * 4 + ct] = *(const bf16x8*)(wmat + (size_t)(ct * 16 + lo) * C_ + kbase);
  }
  return r;
}

__device__ __forceinline__ void computeg(const Grp& g, f32x4 acc[4]) {
  #pragma unroll
  for (int c = 0; c < 2; ++c) {
    bf16x8 af;
    #pragma unroll
    for (int j = 0; j < 4; ++j) {
      af[j]     = f2bf(g.x[c * 2][j]);
      af[4 + j] = f2bf(g.x[c * 2 + 1][j]);
    }
    #pragma unroll
    for (int ct = 0; ct < 4; ++ct)
      acc[ct] = __builtin_amdgcn_mfma_f32_16x16x32_bf16(af, g.b[c * 4 + ct], acc[ct], 0, 0, 0);
  }
}

__global__ __launch_bounds__(256) void qkv_gemm(
    const float* __restrict__ x, const short* __restrict__ wt,
    const float* __restrict__ bq, const float* __restrict__ bk,
    const float* __restrict__ bv,
    short* __restrict__ qb, short* __restrict__ kb, short* __restrict__ vb) {
  const int wid = blockIdx.x * 4 + (threadIdx.x >> 6);  // 0..3071
  const int mat = wid % 3;
  const int rt = wid / 3;              // 0..1023 row tiles of 16
  const int l = threadIdx.x & 63;
  const int lo = l & 15, hi = l >> 4;

  const float* xrow = x + (size_t)(rt * 16 + lo) * C_ + hi * 8;
  const short* wmat = wt + (size_t)mat * H_ * C_ + hi * 8;

  f32x4 acc[4];
  #pragma unroll
  for (int ct = 0; ct < 4; ++ct) acc[ct] = (f32x4){0.f, 0.f, 0.f, 0.f};

  // 12 groups of 64-k, explicit double buffer (A/B named, all-static)
  Grp A = loadg(xrow, wmat, 0, lo);
  Grp Bg;
  #pragma unroll
  for (int gg = 0; gg < 6; ++gg) {
    Bg = loadg(xrow, wmat, 2 * gg + 1, lo);
    computeg(A, acc);
    if (gg < 5) A = loadg(xrow, wmat, 2 * gg + 2, lo);
    computeg(Bg, acc);
  }

  const float* bias = (mat == 0) ? bq : (mat == 1) ? bk : bv;
  short* ob = (mat == 0) ? qb : (mat == 1) ? kb : vb;
  #pragma unroll
  for (int ct = 0; ct < 4; ++ct) {
    const float bias_v = bias[ct * 16 + lo];
    #pragma unroll
    for (int r = 0; r < 4; ++r) {
      const int row = rt * 16 + hi * 4 + r;
      ob[(size_t)row * H_ + ct * 16 + lo] = f2bf(acc[ct][r] + bias_v);
    }
  }
}

// ---------------------------------------------------------------------------
// Kernel 3: V transpose — Vt[b][n][t] = v[b][t][n] (bf16), via LDS tiles.
// ---------------------------------------------------------------------------
__global__ __launch_bounds__(256) void vtrans(const short* __restrict__ vb,
                                              short* __restrict__ vt) {
  __shared__ short tile[64][66];
  const int b = blockIdx.y;
  const int tb = blockIdx.x * 64;
  const int tid = threadIdx.x;

  {
    const int tt = tid >> 2, c = (tid & 3) * 16;
    const short* src = vb + (size_t)(b * T_ + tb + tt) * H_ + c;
    bf16x8 v0 = *(const bf16x8*)(src);
    bf16x8 v1 = *(const bf16x8*)(src + 8);
    #pragma unroll
    for (int j = 0; j < 8; ++j) { tile[tt][c + j] = v0[j]; tile[tt][c + 8 + j] = v1[j]; }
  }
  __syncthreads();
  {
    const int n = tid >> 2, toff = (tid & 3) * 16;
    short* dst = vt + ((size_t)(b * H_ + n)) * T_ + tb + toff;
    bf16x8 o0, o1;
    #pragma unroll
    for (int j = 0; j < 8; ++j) { o0[j] = tile[toff + j][n]; o1[j] = tile[toff + 8 + j][n]; }
    *(bf16x8*)(dst) = o0;
    *(bf16x8*)(dst + 8) = o1;
  }
}

// ---------------------------------------------------------------------------
// Kernel 4: flash attention, 4-way KV-split. Block = 256 threads = 4 waves,
// all share one 16-q-row tile; wave w processes a contiguous quarter of the
// KV tiles, partials merged through LDS (flash-decoding style).
// ---------------------------------------------------------------------------
__global__ __launch_bounds__(256) void flash(
    const short* __restrict__ qb, const short* __restrict__ kb,
    const short* __restrict__ vt, float* __restrict__ out) {
  __shared__ short p_lds[4][16][72];   // per-wave P tile (bf16)
  __shared__ float o_sh[4][16][64];    // per-wave partial O
  __shared__ float ml_sh[4][2][16];    // per-wave [m; l] per row

  const int qt = (int)gridDim.x - 1 - (int)blockIdx.x;  // big tiles first
  const int b = blockIdx.y;
  const int w = threadIdx.x >> 6;
  const int l = threadIdx.x & 63;
  const int lo = l & 15, hi = l >> 4;

  const int dtile = qt >> 2;            // diagonal KV tile index
  const int ntot = dtile + 1;           // total KV tiles for this q tile
  const int span = (ntot + 3) >> 2;
  const int kv0 = w * span;
  const int kv1 = min(ntot, kv0 + span);
  const int qr = qt & 3;

  const short* qrow = qb + (size_t)(b * T_ + qt * 16 + lo) * H_;
  bf16x8 qf0 = *(const bf16x8*)(qrow + hi * 8);
  bf16x8 qf1 = *(const bf16x8*)(qrow + 32 + hi * 8);

  float m[4], lsum[4];
  f32x4 oacc[4];
  #pragma unroll
  for (int r = 0; r < 4; ++r) { m[r] = -1e30f; lsum[r] = 0.f; }
  #pragma unroll
  for (int dt = 0; dt < 4; ++dt) oacc[dt] = (f32x4){0.f, 0.f, 0.f, 0.f};

  for (int kvt = kv0; kvt < kv1; ++kvt) {
    const bool diag = (kvt == dtile);
    const int nct = diag ? (qr + 1) : 4;  // wave-uniform

    // S = Q K^T  (16 x 64)
    f32x4 sv[4];
    #pragma unroll
    for (int ct = 0; ct < 4; ++ct) sv[ct] = (f32x4){0.f, 0.f, 0.f, 0.f};
    #pragma unroll
    for (int ct = 0; ct < 4; ++ct) {
      if (ct < nct) {
        const short* krow = kb + (size_t)(b * T_ + kvt * 64 + ct * 16 + lo) * H_;
        bf16x8 kf0 = *(const bf16x8*)(krow + hi * 8);
        bf16x8 kf1 = *(const bf16x8*)(krow + 32 + hi * 8);
        sv[ct] = __builtin_amdgcn_mfma_f32_16x16x32_bf16(qf0, kf0, sv[ct], 0, 0, 0);
        sv[ct] = __builtin_amdgcn_mfma_f32_16x16x32_bf16(qf1, kf1, sv[ct], 0, 0, 0);
      }
    }

    // scale + causal mask
    #pragma unroll
    for (int ct = 0; ct < 4; ++ct) {
      #pragma unroll
      for (int r = 0; r < 4; ++r) {
        float s = (ct < nct) ? sv[ct][r] * 0.125f : -1e30f;
        if (diag && ct == qr && lo > hi * 4 + r) s = -1e30f;
        sv[ct][r] = s;
      }
    }

    // online softmax per row
    #pragma unroll
    for (int r = 0; r < 4; ++r) {
      float tmax = fmaxf(fmaxf(sv[0][r], sv[1][r]), fmaxf(sv[2][r], sv[3][r]));
      #pragma unroll
      for (int msk = 1; msk < 16; msk <<= 1) tmax = fmaxf(tmax, __shfl_xor(tmax, msk));
      const float mn = fmaxf(m[r], tmax);
      const float corr = __expf(m[r] - mn);
      m[r] = mn;
      float psum = 0.f;
      #pragma unroll
      for (int ct = 0; ct < 4; ++ct) {
        float p = __expf(sv[ct][r] - mn);
        sv[ct][r] = p;
        psum += p;
      }
      #pragma unroll
      for (int msk = 1; msk < 16; msk <<= 1) psum += __shfl_xor(psum, msk);
      lsum[r] = lsum[r] * corr + psum;
      #pragma unroll
      for (int dt = 0; dt < 4; ++dt) oacc[dt][r] *= corr;
    }

    // P -> bf16 -> LDS (per-wave buffer; same-wave RAW handled by lgkmcnt)
    #pragma unroll
    for (int ct = 0; ct < 4; ++ct) {
      #pragma unroll
      for (int r = 0; r < 4; ++r) {
        p_lds[w][hi * 4 + r][ct * 16 + lo] = f2bf(sv[ct][r]);
      }
    }

    // O += P V
    bf16x8 pa0 = *(const bf16x8*)(&p_lds[w][lo][hi * 8]);
    bf16x8 pa1 = *(const bf16x8*)(&p_lds[w][lo][32 + hi * 8]);
    #pragma unroll
    for (int dt = 0; dt < 4; ++dt) {
      const short* vrow = vt + (size_t)(b * H_ + dt * 16 + lo) * T_ + kvt * 64;
      bf16x8 vf0 = *(const bf16x8*)(vrow + hi * 8);
      bf16x8 vf1 = *(const bf16x8*)(vrow + 32 + hi * 8);
      oacc[dt] = __builtin_amdgcn_mfma_f32_16x16x32_bf16(pa0, vf0, oacc[dt], 0, 0, 0);
      oacc[dt] = __builtin_amdgcn_mfma_f32_16x16x32_bf16(pa1, vf1, oacc[dt], 0, 0, 0);
    }
  }

  // publish partials
  #pragma unroll
  for (int dt = 0; dt < 4; ++dt)
    #pragma unroll
    for (int r = 0; r < 4; ++r)
      o_sh[w][hi * 4 + r][dt * 16 + lo] = oacc[dt][r];
  if (lo == 0) {
    #pragma unroll
    for (int r = 0; r < 4; ++r) {
      ml_sh[w][0][hi * 4 + r] = m[r];
      ml_sh[w][1][hi * 4 + r] = lsum[r];
    }
  }
  __syncthreads();

  // merge: thread tid -> row = tid>>4, cols (tid&15)*4 .. +3
  {
    const int row = threadIdx.x >> 4;
    const int c0 = (threadIdx.x & 15) * 4;
    float M = fmaxf(fmaxf(ml_sh[0][0][row], ml_sh[1][0][row]),
                    fmaxf(ml_sh[2][0][row], ml_sh[3][0][row]));
    float e[4];
    float L = 0.f;
    #pragma unroll
    for (int w2 = 0; w2 < 4; ++w2) {
      e[w2] = __expf(ml_sh[w2][0][row] - M);
      L += ml_sh[w2][1][row] * e[w2];
    }
    f32x4 o;
    #pragma unroll
    for (int j = 0; j < 4; ++j) {
      float O = 0.f;
      #pragma unroll
      for (int w2 = 0; w2 < 4; ++w2) O += e[w2] * o_sh[w2][row][c0 + j];
      o[j] = O / L;
    }
    *(f32x4*)(out + (size_t)(b * T_ + qt * 16 + row) * H_ + c0) = o;
  }
}

// ---------------------------------------------------------------------------
extern "C" void kernel_launch(void* const* d_in, const int* in_sizes, int n_in,
                              void* d_out, int out_size, void* d_ws, size_t ws_size,
                              hipStream_t stream) {
  const float* x  = (const float*)d_in[0];
  const float* Wq = (const float*)d_in[1];
  const float* bq = (const float*)d_in[2];
  const float* Wk = (const float*)d_in[3];
  const float* bk = (const float*)d_in[4];
  const float* Wv = (const float*)d_in[5];
  const float* bv = (const float*)d_in[6];
  float* out = (float*)d_out;

  // workspace layout (shorts): wt | qb | kb | vb | vt
  short* wt = (short*)d_ws;
  short* qb = wt + (size_t)3 * H_ * C_;
  short* kb = qb + (size_t)B_ * T_ * H_;
  short* vb = kb + (size_t)B_ * T_ * H_;
  short* vtb = vb + (size_t)B_ * T_ * H_;

  prep_w<<<dim3((3 * H_ * C_ + 255) / 256), dim3(256), 0, stream>>>(Wq, Wk, Wv, wt);
  qkv_gemm<<<dim3(768), dim3(256), 0, stream>>>(x, wt, bq, bk, bv, qb, kb, vb);
  vtrans<<<dim3(T_ / 64, B_), dim3(256), 0, stream>>>(vb, vtb);
  flash<<<dim3(T_ / 16, B_), dim3(256), 0, stream>>>(qb, kb, vtb, out);
}

// Round 4
// 63.392 us; speedup vs baseline: 17.0575x; 1.4600x over previous
//
#include <hip/hip_runtime.h>
#include <math.h>

// Problem dims (fixed by reference)
#define B_ 16
#define T_ 1024
#define C_ 768
#define H_ 64

typedef __attribute__((ext_vector_type(8))) short bf16x8;
typedef __attribute__((ext_vector_type(4))) float f32x4;

// fp32 -> bf16 (round-to-nearest-even)
__device__ __forceinline__ short f2bf(float f) {
  union { float f; unsigned u; } un;
  un.f = f;
  unsigned r = un.u + 0x7FFFu + ((un.u >> 16) & 1u);
  return (short)(r >> 16);
}

// ---------------------------------------------------------------------------
// Kernel 1: W prep in MFMA fragment order.
// frag_id = ks*12 + ct  (ks = k-step of 32, ct = global col-tile 0..11,
// mat = ct>>2). Element: wfrag[frag_id*512 + l*8 + j] = W_mat[k][col], with
// col = (ct&3)*16 + (l&15), k = ks*32 + (l>>4)*8 + j.  -> each B-frag load in
// the GEMM is one fully coalesced 1KB/wave instruction.
// ---------------------------------------------------------------------------
__global__ __launch_bounds__(256) void prep_w(
    const float* __restrict__ Wq, const float* __restrict__ Wk,
    const float* __restrict__ Wv, short* __restrict__ wfrag) {
  const int o = blockIdx.x * 256 + threadIdx.x;   // 0..147455
  const int j = o & 7;
  const int l = (o >> 3) & 63;
  const int fid = o >> 9;
  const int ct = fid % 12;
  const int ks = fid / 12;
  const int mat = ct >> 2;
  const int col = (ct & 3) * 16 + (l & 15);
  const int k = ks * 32 + (l >> 4) * 8 + j;
  const float* W = (mat == 0) ? Wq : (mat == 1) ? Wk : Wv;
  wfrag[o] = f2bf(W[(size_t)k * H_ + col]);
}

// ---------------------------------------------------------------------------
// Kernel 2: QKV projection. Block = 128 thr = 2 waves, one 16-row tile.
// Wave w handles K-half w (384 k) for ALL 192 output cols (q|k|v), partials
// merged through LDS. x staged per-wave via global_load_lds (pre-swizzled
// source, XOR-swizzled ds_read), double-buffered, no barriers in main loop.
// ---------------------------------------------------------------------------
#define QKV_LDSF 6400  // floats: staging 2 waves * 2 bufs * 1024; pool 2*16*196

__global__ __launch_bounds__(128, 2) void qkv_gemm(
    const float* __restrict__ x, const short* __restrict__ wfrag,
    const float* __restrict__ bq, const float* __restrict__ bk,
    const float* __restrict__ bv, short* __restrict__ qkv) {
  __shared__ float lds[QKV_LDSF];
  const int rt = blockIdx.x;            // 16-row tile
  const int w  = threadIdx.x >> 6;      // wave = K-half
  const int l  = threadIdx.x & 63;
  const int lo = l & 15, hi = l >> 4;
  const int kh = w;

  float* stg = lds + w * 2048;          // 2 bufs x 1024 floats (4KB each)
  const char* xb = (const char*)(x + (size_t)rt * 16 * C_ + kh * 384);

  // stage chunk c (64 k-floats x 16 rows = 4KB) into buf: 4 global_load_lds.
  // LDS linear [row][256B]; global source pre-swizzled so reads can XOR-swz.
  auto STAGE = [&](int buf, int c) {
    #pragma unroll
    for (int s = 0; s < 4; ++s) {
      const int r = s * 4 + hi;
      const char* src = xb + (size_t)r * (C_ * 4) + (size_t)c * 256
                        + ((lo * 16) ^ ((r & 7) << 4));
      float* dst = stg + buf * 1024 + s * 256;  // wave-uniform base
      __builtin_amdgcn_global_load_lds(
          (const __attribute__((address_space(1))) void*)src,
          (__attribute__((address_space(3))) void*)dst, 16, 0, 0);
    }
  };

  f32x4 acc[12];
  #pragma unroll
  for (int ct = 0; ct < 12; ++ct) acc[ct] = (f32x4){0.f, 0.f, 0.f, 0.f};

  STAGE(0, 0);

  #pragma unroll
  for (int c = 0; c < 6; ++c) {
    const int buf = c & 1;
    __builtin_amdgcn_sched_barrier(0);
    // ---- section 1: issue W-frag loads for this chunk (24 coalesced 16B/lane)
    bf16x8 wf0[12], wf1[12];
    const int ksb = kh * 12 + c * 2;
    #pragma unroll
    for (int ct = 0; ct < 12; ++ct) {
      wf0[ct] = *(const bf16x8*)(wfrag + ((size_t)(ksb * 12 + ct) << 9) + l * 8);
      wf1[ct] = *(const bf16x8*)(wfrag + ((size_t)((ksb + 1) * 12 + ct) << 9) + l * 8);
    }
    __builtin_amdgcn_sched_barrier(0);
    // ---- section 2: stage next chunk (stays in flight across compute)
    if (c < 5) STAGE(buf ^ 1, c + 1);
    __builtin_amdgcn_sched_barrier(0);
    // ---- section 3: wait for THIS chunk's stage only.
    // outstanding worst-case: stage(c)=4 (oldest) + W(c)=24 + stage(c+1)=4
    if (c < 5) { asm volatile("s_waitcnt vmcnt(28)" ::: "memory"); }
    else       { asm volatile("s_waitcnt vmcnt(24)" ::: "memory"); }
    __builtin_amdgcn_sched_barrier(0);
    // ---- section 4: A-frags from LDS (XOR-swz) + cvt + 24 MFMAs
    bf16x8 af0, af1;
    {
      const char* rp = (const char*)(stg + buf * 1024) + lo * 256;
      const int sw = (lo & 7) << 4;
      f32x4 x0 = *(const f32x4*)(rp + ((hi * 32)       ^ sw));
      f32x4 x1 = *(const f32x4*)(rp + ((hi * 32 + 16)  ^ sw));
      f32x4 x2 = *(const f32x4*)(rp + ((128 + hi * 32)      ^ sw));
      f32x4 x3 = *(const f32x4*)(rp + ((128 + hi * 32 + 16) ^ sw));
      #pragma unroll
      for (int j = 0; j < 4; ++j) {
        af0[j] = f2bf(x0[j]); af0[4 + j] = f2bf(x1[j]);
        af1[j] = f2bf(x2[j]); af1[4 + j] = f2bf(x3[j]);
      }
    }
    __builtin_amdgcn_s_setprio(1);
    #pragma unroll
    for (int ct = 0; ct < 12; ++ct)
      acc[ct] = __builtin_amdgcn_mfma_f32_16x16x32_bf16(af0, wf0[ct], acc[ct], 0, 0, 0);
    #pragma unroll
    for (int ct = 0; ct < 12; ++ct)
      acc[ct] = __builtin_amdgcn_mfma_f32_16x16x32_bf16(af1, wf1[ct], acc[ct], 0, 0, 0);
    __builtin_amdgcn_s_setprio(0);
  }

  // ---- merge K-halves through LDS (pool overlaps staging region; barrier
  // first so the other wave is done reading its staging buffers)
  __syncthreads();
  #pragma unroll
  for (int ct = 0; ct < 12; ++ct)
    #pragma unroll
    for (int r = 0; r < 4; ++r)
      lds[w * 3136 + (hi * 4 + r) * 196 + ct * 16 + lo] = acc[ct][r];
  __syncthreads();

  {
    const int row = threadIdx.x >> 3;          // 0..15
    const int c0 = (threadIdx.x & 7) * 24;     // 0..168
    bf16x8 o0, o1, o2;
    #pragma unroll
    for (int j = 0; j < 24; ++j) {
      const int col = c0 + j;
      float s = lds[row * 196 + col] + lds[3136 + row * 196 + col];
      const int mat = col >> 6;
      const float* bb = (mat == 0) ? bq : (mat == 1) ? bk : bv;
      s += bb[col & 63];
      const short v = f2bf(s);
      if (j < 8) o0[j] = v; else if (j < 16) o1[j - 8] = v; else o2[j - 16] = v;
    }
    short* op = qkv + ((size_t)(rt * 16 + row)) * 192 + c0;
    *(bf16x8*)(op)      = o0;
    *(bf16x8*)(op + 8)  = o1;
    *(bf16x8*)(op + 16) = o2;
  }
}

// ---------------------------------------------------------------------------
// Kernel 3: V transpose — Vt[b][n][t] = v[b][t][n] (bf16), via LDS tiles.
// v rows live at qkv[row][128..191], row stride 192.
// ---------------------------------------------------------------------------
__global__ __launch_bounds__(256) void vtrans(const short* __restrict__ qkv,
                                              short* __restrict__ vt) {
  __shared__ short tile[64][66];
  const int b = blockIdx.y;
  const int tb = blockIdx.x * 64;
  const int tid = threadIdx.x;

  {
    const int tt = tid >> 2, c = (tid & 3) * 16;
    const short* src = qkv + (size_t)(b * T_ + tb + tt) * 192 + 128 + c;
    bf16x8 v0 = *(const bf16x8*)(src);
    bf16x8 v1 = *(const bf16x8*)(src + 8);
    #pragma unroll
    for (int j = 0; j < 8; ++j) { tile[tt][c + j] = v0[j]; tile[tt][c + 8 + j] = v1[j]; }
  }
  __syncthreads();
  {
    const int n = tid >> 2, toff = (tid & 3) * 16;
    short* dst = vt + ((size_t)(b * H_ + n)) * T_ + tb + toff;
    bf16x8 o0, o1;
    #pragma unroll
    for (int j = 0; j < 8; ++j) { o0[j] = tile[toff + j][n]; o1[j] = tile[toff + 8 + j][n]; }
    *(bf16x8*)(dst) = o0;
    *(bf16x8*)(dst + 8) = o1;
  }
}

// ---------------------------------------------------------------------------
// Kernel 4: flash attention, 4-way KV-split (unchanged structure; strides
// adapted to interleaved qkv buffer; setprio around MFMA clusters).
// ---------------------------------------------------------------------------
__global__ __launch_bounds__(256) void flash(
    const short* __restrict__ qkv, const short* __restrict__ vt,
    float* __restrict__ out) {
  __shared__ short p_lds[4][16][72];
  __shared__ float o_sh[4][16][64];
  __shared__ float ml_sh[4][2][16];

  const int qt = (int)gridDim.x - 1 - (int)blockIdx.x;
  const int b = blockIdx.y;
  const int w = threadIdx.x >> 6;
  const int l = threadIdx.x & 63;
  const int lo = l & 15, hi = l >> 4;

  const int dtile = qt >> 2;
  const int ntot = dtile + 1;
  const int span = (ntot + 3) >> 2;
  const int kv0 = w * span;
  const int kv1 = min(ntot, kv0 + span);
  const int qr = qt & 3;

  const short* qrow = qkv + (size_t)(b * T_ + qt * 16 + lo) * 192;  // q at +0
  bf16x8 qf0 = *(const bf16x8*)(qrow + hi * 8);
  bf16x8 qf1 = *(const bf16x8*)(qrow + 32 + hi * 8);

  float m[4], lsum[4];
  f32x4 oacc[4];
  #pragma unroll
  for (int r = 0; r < 4; ++r) { m[r] = -1e30f; lsum[r] = 0.f; }
  #pragma unroll
  for (int dt = 0; dt < 4; ++dt) oacc[dt] = (f32x4){0.f, 0.f, 0.f, 0.f};

  for (int kvt = kv0; kvt < kv1; ++kvt) {
    const bool diag = (kvt == dtile);
    const int nct = diag ? (qr + 1) : 4;

    f32x4 sv[4];
    #pragma unroll
    for (int ct = 0; ct < 4; ++ct) sv[ct] = (f32x4){0.f, 0.f, 0.f, 0.f};
    __builtin_amdgcn_s_setprio(1);
    #pragma unroll
    for (int ct = 0; ct < 4; ++ct) {
      if (ct < nct) {
        const short* krow = qkv + (size_t)(b * T_ + kvt * 64 + ct * 16 + lo) * 192 + 64;
        bf16x8 kf0 = *(const bf16x8*)(krow + hi * 8);
        bf16x8 kf1 = *(const bf16x8*)(krow + 32 + hi * 8);
        sv[ct] = __builtin_amdgcn_mfma_f32_16x16x32_bf16(qf0, kf0, sv[ct], 0, 0, 0);
        sv[ct] = __builtin_amdgcn_mfma_f32_16x16x32_bf16(qf1, kf1, sv[ct], 0, 0, 0);
      }
    }
    __builtin_amdgcn_s_setprio(0);

    #pragma unroll
    for (int ct = 0; ct < 4; ++ct) {
      #pragma unroll
      for (int r = 0; r < 4; ++r) {
        float s = (ct < nct) ? sv[ct][r] * 0.125f : -1e30f;
        if (diag && ct == qr && lo > hi * 4 + r) s = -1e30f;
        sv[ct][r] = s;
      }
    }

    #pragma unroll
    for (int r = 0; r < 4; ++r) {
      float tmax = fmaxf(fmaxf(sv[0][r], sv[1][r]), fmaxf(sv[2][r], sv[3][r]));
      #pragma unroll
      for (int msk = 1; msk < 16; msk <<= 1) tmax = fmaxf(tmax, __shfl_xor(tmax, msk));
      const float mn = fmaxf(m[r], tmax);
      const float corr = __expf(m[r] - mn);
      m[r] = mn;
      float psum = 0.f;
      #pragma unroll
      for (int ct = 0; ct < 4; ++ct) {
        float p = __expf(sv[ct][r] - mn);
        sv[ct][r] = p;
        psum += p;
      }
      #pragma unroll
      for (int msk = 1; msk < 16; msk <<= 1) psum += __shfl_xor(psum, msk);
      lsum[r] = lsum[r] * corr + psum;
      #pragma unroll
      for (int dt = 0; dt < 4; ++dt) oacc[dt][r] *= corr;
    }

    #pragma unroll
    for (int ct = 0; ct < 4; ++ct) {
      #pragma unroll
      for (int r = 0; r < 4; ++r) {
        p_lds[w][hi * 4 + r][ct * 16 + lo] = f2bf(sv[ct][r]);
      }
    }

    bf16x8 pa0 = *(const bf16x8*)(&p_lds[w][lo][hi * 8]);
    bf16x8 pa1 = *(const bf16x8*)(&p_lds[w][lo][32 + hi * 8]);
    __builtin_amdgcn_s_setprio(1);
    #pragma unroll
    for (int dt = 0; dt < 4; ++dt) {
      const short* vrow = vt + (size_t)(b * H_ + dt * 16 + lo) * T_ + kvt * 64;
      bf16x8 vf0 = *(const bf16x8*)(vrow + hi * 8);
      bf16x8 vf1 = *(const bf16x8*)(vrow + 32 + hi * 8);
      oacc[dt] = __builtin_amdgcn_mfma_f32_16x16x32_bf16(pa0, vf0, oacc[dt], 0, 0, 0);
      oacc[dt] = __builtin_amdgcn_mfma_f32_16x16x32_bf16(pa1, vf1, oacc[dt], 0, 0, 0);
    }
    __builtin_amdgcn_s_setprio(0);
  }

  #pragma unroll
  for (int dt = 0; dt < 4; ++dt)
    #pragma unroll
    for (int r = 0; r < 4; ++r)
      o_sh[w][hi * 4 + r][dt * 16 + lo] = oacc[dt][r];
  if (lo == 0) {
    #pragma unroll
    for (int r = 0; r < 4; ++r) {
      ml_sh[w][0][hi * 4 + r] = m[r];
      ml_sh[w][1][hi * 4 + r] = lsum[r];
    }
  }
  __syncthreads();

  {
    const int row = threadIdx.x >> 4;
    const int c0 = (threadIdx.x & 15) * 4;
    float M = fmaxf(fmaxf(ml_sh[0][0][row], ml_sh[1][0][row]),
                    fmaxf(ml_sh[2][0][row], ml_sh[3][0][row]));
    float e[4];
    float L = 0.f;
    #pragma unroll
    for (int w2 = 0; w2 < 4; ++w2) {
      e[w2] = __expf(ml_sh[w2][0][row] - M);
      L += ml_sh[w2][1][row] * e[w2];
    }
    f32x4 o;
    #pragma unroll
    for (int j = 0; j < 4; ++j) {
      float O = 0.f;
      #pragma unroll
      for (int w2 = 0; w2 < 4; ++w2) O += e[w2] * o_sh[w2][row][c0 + j];
      o[j] = O / L;
    }
    *(f32x4*)(out + (size_t)(b * T_ + qt * 16 + row) * H_ + c0) = o;
  }
}

// ---------------------------------------------------------------------------
extern "C" void kernel_launch(void* const* d_in, const int* in_sizes, int n_in,
                              void* d_out, int out_size, void* d_ws, size_t ws_size,
                              hipStream_t stream) {
  const float* x  = (const float*)d_in[0];
  const float* Wq = (const float*)d_in[1];
  const float* bq = (const float*)d_in[2];
  const float* Wk = (const float*)d_in[3];
  const float* bk = (const float*)d_in[4];
  const float* Wv = (const float*)d_in[5];
  const float* bv = (const float*)d_in[6];
  float* out = (float*)d_out;

  // workspace layout (shorts): wfrag | qkv(interleaved) | vt
  short* wfrag = (short*)d_ws;
  short* qkv = wfrag + (size_t)3 * H_ * C_;          // 147456
  short* vtb = qkv + (size_t)B_ * T_ * 192;          // +3145728

  prep_w<<<dim3(576), dim3(256), 0, stream>>>(Wq, Wk, Wv, wfrag);
  qkv_gemm<<<dim3(1024), dim3(128), 0, stream>>>(x, wfrag, bq, bk, bv, qkv);
  vtrans<<<dim3(T_ / 64, B_), dim3(256), 0, stream>>>(qkv, vtb);
  flash<<<dim3(T_ / 16, B_), dim3(256), 0, stream>>>(qkv, vtb, out);
}